// Round 2
// baseline (563.898 us; speedup 1.0000x reference)
//
#include <hip/hip_runtime.h>
#include <math.h>

// (32, 3, 1024, 1024) fp32, 8x8 window max/min pool -> 20*ln(max/(min+eps))
// masked by (max != min), summed, scaled by w*w/(H*W)/B -> scalar.
//
// Coalesced layout: each thread loads one float4 (4 cols); a 256-thread block
// covers one full 4KB image row per load instruction (lane-contiguous 16B).
// Block = one window-row band (8 image rows) of one plane. Window (8 cols) =
// thread pair (2i, 2i+1) combined via shfl_xor(1).

#define IMG_ROWS 1024
#define IMG_COLS 1024
#define WIN 8
#define NPLANE (32 * 3)
#define BANDS (IMG_ROWS / WIN)   // 128 window-rows per plane

__global__ __launch_bounds__(256) void eme_window_kernel(
    const float* __restrict__ in, float* __restrict__ out) {
    const int blk   = blockIdx.x;        // 0 .. NPLANE*BANDS - 1
    const int band  = blk & (BANDS - 1); // window-row within plane
    const int plane = blk >> 7;          // b*3 + c
    const int tid   = threadIdx.x;       // 0..255, covers 4 cols each

    const float* base = in + (size_t)plane * IMG_ROWS * IMG_COLS
                           + (size_t)band * WIN * IMG_COLS
                           + (size_t)tid * 4;

    float mx = -INFINITY;
    float mn =  INFINITY;
#pragma unroll
    for (int r = 0; r < WIN; ++r) {
        float4 a = *(const float4*)(base + (size_t)r * IMG_COLS);
        mx = fmaxf(mx, fmaxf(fmaxf(a.x, a.y), fmaxf(a.z, a.w)));
        mn = fminf(mn, fminf(fminf(a.x, a.y), fminf(a.z, a.w)));
    }

    // Pair (2i, 2i+1) -> full 8-col window max/min (both threads get it).
    mx = fmaxf(mx, __shfl_xor(mx, 1, 64));
    mn = fminf(mn, __shfl_xor(mn, 1, 64));

    float val = 0.0f;
    if (((tid & 1) == 0) && (mx - mn != 0.0f)) {
        val = 20.0f * logf(mx / (mn + 1e-4f));
    }

    // wave (64-lane) shuffle reduction
#pragma unroll
    for (int off = 32; off > 0; off >>= 1) {
        val += __shfl_down(val, off, 64);
    }

    __shared__ float wsum[4];
    const int lane = tid & 63;
    const int wave = tid >> 6;
    if (lane == 0) wsum[wave] = val;
    __syncthreads();
    if (tid == 0) {
        float s = wsum[0] + wsum[1] + wsum[2] + wsum[3];
        const float scale = (float)(WIN * WIN) /
                            ((float)IMG_ROWS * (float)IMG_COLS) / 32.0f;
        atomicAdd(out, s * scale);
    }
}

extern "C" void kernel_launch(void* const* d_in, const int* in_sizes, int n_in,
                              void* d_out, int out_size, void* d_ws, size_t ws_size,
                              hipStream_t stream) {
    const float* y_pred = (const float*)d_in[0];
    float* out = (float*)d_out;

    // d_out is poisoned to 0xAA before every timed launch — zero it on-stream.
    hipMemsetAsync(out, 0, sizeof(float), stream);

    const int grid = NPLANE * BANDS;  // 12288 blocks x 256 threads
    eme_window_kernel<<<grid, 256, 0, stream>>>(y_pred, out);
}

// Round 3
// 522.698 us; speedup vs baseline: 1.0788x; 1.0788x over previous
//
#include <hip/hip_runtime.h>
#include <math.h>

// (32, 3, 1024, 1024) fp32, 8x8 window max/min pool -> 20*ln(max/(min+eps))
// masked by (max != min), summed, scaled by w*w/(H*W)/B -> scalar.
//
// Stage 1: one block per window-row band (8 rows of one plane). Each thread
// loads one float4/row (lane-contiguous 16B => 1KB/wave per instruction),
// pairs (2i,2i+1) combine via shfl_xor(1) into the 8-col window. Block
// partial is STORED to ws[block] — no atomics (12288 same-address fp32
// atomics cost ~100us of serialization; measured R0->R1: +6144 atomics
// <=> +51us).
// Stage 2: single block reduces the 12288 partials and writes out[0].

#define IMG_ROWS 1024
#define IMG_COLS 1024
#define WIN 8
#define NPLANE (32 * 3)
#define BANDS (IMG_ROWS / WIN)      // 128 window-row bands per plane
#define NBLOCKS (NPLANE * BANDS)    // 12288 stage-1 blocks

__global__ __launch_bounds__(256) void eme_stage1(
    const float* __restrict__ in, float* __restrict__ partial) {
    const int blk   = blockIdx.x;
    const int band  = blk & (BANDS - 1);
    const int plane = blk >> 7;
    const int tid   = threadIdx.x;

    const float* base = in + (size_t)plane * IMG_ROWS * IMG_COLS
                           + (size_t)band * WIN * IMG_COLS
                           + (size_t)tid * 4;

    float mx = -INFINITY;
    float mn =  INFINITY;
#pragma unroll
    for (int r = 0; r < WIN; ++r) {
        float4 a = *(const float4*)(base + (size_t)r * IMG_COLS);
        mx = fmaxf(mx, fmaxf(fmaxf(a.x, a.y), fmaxf(a.z, a.w)));
        mn = fminf(mn, fminf(fminf(a.x, a.y), fminf(a.z, a.w)));
    }

    // Pair (2i, 2i+1) -> full 8-col window max/min.
    mx = fmaxf(mx, __shfl_xor(mx, 1, 64));
    mn = fminf(mn, __shfl_xor(mn, 1, 64));

    float val = 0.0f;
    if (((tid & 1) == 0) && (mx - mn != 0.0f)) {
        val = 20.0f * logf(mx / (mn + 1e-4f));
    }

#pragma unroll
    for (int off = 32; off > 0; off >>= 1) {
        val += __shfl_down(val, off, 64);
    }

    __shared__ float wsum[4];
    const int lane = tid & 63;
    const int wave = tid >> 6;
    if (lane == 0) wsum[wave] = val;
    __syncthreads();
    if (tid == 0) {
        const float scale = (float)(WIN * WIN) /
                            ((float)IMG_ROWS * (float)IMG_COLS) / 32.0f;
        partial[blk] = (wsum[0] + wsum[1] + wsum[2] + wsum[3]) * scale;
    }
}

__global__ __launch_bounds__(256) void eme_stage2(
    const float* __restrict__ partial, float* __restrict__ out) {
    const int tid = threadIdx.x;
    float s = 0.0f;
    for (int i = tid; i < NBLOCKS; i += 256) s += partial[i];

#pragma unroll
    for (int off = 32; off > 0; off >>= 1) {
        s += __shfl_down(s, off, 64);
    }

    __shared__ float wsum[4];
    const int lane = tid & 63;
    const int wave = tid >> 6;
    if (lane == 0) wsum[wave] = s;
    __syncthreads();
    if (tid == 0) {
        out[0] = wsum[0] + wsum[1] + wsum[2] + wsum[3];
    }
}

extern "C" void kernel_launch(void* const* d_in, const int* in_sizes, int n_in,
                              void* d_out, int out_size, void* d_ws, size_t ws_size,
                              hipStream_t stream) {
    const float* y_pred = (const float*)d_in[0];
    float* partial = (float*)d_ws;   // 12288 floats = 48 KB scratch
    float* out = (float*)d_out;

    eme_stage1<<<NBLOCKS, 256, 0, stream>>>(y_pred, partial);
    eme_stage2<<<1, 256, 0, stream>>>(partial, out);
}